// Round 5
// baseline (130.655 us; speedup 1.0000x reference)
//
#include <hip/hip_runtime.h>

#define H_ 8
#define D_ 32
#define B_ 32
#define N_ 4096
#define C_ 256
#define EPS_ 1e-5f

typedef __attribute__((ext_vector_type(8))) short bf16x8;
typedef __attribute__((ext_vector_type(4))) float f32x4;

__device__ __forceinline__ short f2bf(float f) {
    unsigned u = __builtin_bit_cast(unsigned, f);
    unsigned r = (u + 0x7FFFu + ((u >> 16) & 1u)) >> 16;
    return (short)r;
}

// physical short-index of (row, col) in ubuf: 80 B row stride + 32 B shift per
// 8-row group -> fragment reads conflict-free (verified R2: 0 conflicts).
__device__ __forceinline__ int uidx(int r, int c) {
    return r * 40 + ((r >> 3) & 3) * 16 + c;
}

// ---------------------------------------------------------------------------
// Kernel 1: per (b,h) accumulate S = U^T U (32x32) and t = colsum(U) via MFMA.
// Grid: B*H*16 = 4096 single-shot blocks (256 rows each), 256 threads.
// Thread tid owns row tid (lane-private LN, no shfl). u-buffer is WAVE-PRIVATE
// (wave w's MFMA reads only rows [64w,64w+64) = rows its own lanes wrote), so
// the hot path has ZERO block barriers — just one lgkmcnt(0) per wave.
// 28 resident waves/CU run fully unsynchronized until the epilogue.
// ---------------------------------------------------------------------------
__global__ __launch_bounds__(256, 4)
void k1_skv(const float* __restrict__ x, float* __restrict__ Sws, float* __restrict__ Tws)
{
    __shared__ short ubuf[256 * 40 + 64];   // 20.6 KB; reused as float scratch

    const int tid  = threadIdx.x;
    const int bh   = blockIdx.x >> 4;
    const int q16  = blockIdx.x & 15;
    const int b    = bh >> 3;
    const int h    = bh & 7;
    const int lane = tid & 63;
    const int wave = tid >> 6;
    const int g    = lane >> 4;      // 0..3 : k-group
    const int cL   = lane & 15;      // 0..15: column within 16-block

    f32x4 acc[2][2] = {};            // S quadrants [ca][cb]
    f32x4 tq[2] = {};                // column sums via ones-MFMA

    bf16x8 ones;
    #pragma unroll
    for (int j = 0; j < 8; ++j) ones[j] = (short)0x3F80;   // bf16 1.0

    // ---- load own row (8 x dwordx4; 2 cache lines per lane, fully used)
    const float* xrow = x + ((size_t)b * N_ + q16 * 256 + tid) * C_ + h * D_;
    float4 xr[8];
    #pragma unroll
    for (int c = 0; c < 8; ++c)
        xr[c] = reinterpret_cast<const float4*>(xrow)[c];

    // ---- LN, fully lane-private
    float sum = 0.f, sq = 0.f;
    #pragma unroll
    for (int c = 0; c < 8; ++c) {
        const float4 a = xr[c];
        sum += a.x + a.y + a.z + a.w;
        sq = fmaf(a.x, a.x, fmaf(a.y, a.y, fmaf(a.z, a.z, fmaf(a.w, a.w, sq))));
    }
    const float m   = sum * (1.f / 32.f);
    const float ss  = fmaxf(sq - sum * m, 0.f);
    const float inv = 1.f / (sqrtf(ss * (1.f / 31.f)) + EPS_);

    // ---- u -> bf16, write own row to LDS (wave-private region)
    {
        const int base = tid * 40 + ((tid >> 3) & 3) * 16;
        #pragma unroll
        for (int q = 0; q < 4; ++q) {
            const float4 a0 = xr[q * 2 + 0];
            const float4 a1 = xr[q * 2 + 1];
            bf16x8 wv;
            wv[0] = f2bf((a0.x - m) * inv); wv[1] = f2bf((a0.y - m) * inv);
            wv[2] = f2bf((a0.z - m) * inv); wv[3] = f2bf((a0.w - m) * inv);
            wv[4] = f2bf((a1.x - m) * inv); wv[5] = f2bf((a1.y - m) * inv);
            wv[6] = f2bf((a1.z - m) * inv); wv[7] = f2bf((a1.w - m) * inv);
            *reinterpret_cast<bf16x8*>(&ubuf[base + q * 8]) = wv;
        }
    }
    // intra-wave write->read ordering only; NO block barrier in hot path
    asm volatile("s_waitcnt lgkmcnt(0)" ::: "memory");

    // ---- fragment + MFMA: wave w owns K-rows [w*64, w*64+64), 2 ks-steps
    #pragma unroll
    for (int ks = 0; ks < 2; ++ks) {
        const int R0 = wave * 64 + ks * 32 + 8 * g;
        bf16x8 F0, F1;
        #pragma unroll
        for (int j = 0; j < 8; ++j) {
            const int base = uidx(R0 + j, cL);
            F0[j] = ubuf[base];
            F1[j] = ubuf[base + 16];
        }
        tq[0] = __builtin_amdgcn_mfma_f32_16x16x32_bf16(ones, F0, tq[0], 0, 0, 0);
        tq[1] = __builtin_amdgcn_mfma_f32_16x16x32_bf16(ones, F1, tq[1], 0, 0, 0);
        acc[0][0] = __builtin_amdgcn_mfma_f32_16x16x32_bf16(F0, F0, acc[0][0], 0, 0, 0);
        acc[0][1] = __builtin_amdgcn_mfma_f32_16x16x32_bf16(F0, F1, acc[0][1], 0, 0, 0);
        acc[1][0] = __builtin_amdgcn_mfma_f32_16x16x32_bf16(F1, F0, acc[1][0], 0, 0, 0);
        acc[1][1] = __builtin_amdgcn_mfma_f32_16x16x32_bf16(F1, F1, acc[1][1], 0, 0, 0);
    }

    // ---- cross-wave S reduce in LDS (2 copies), then 4 atomics/thread
    // C/D layout col=lane&15, row=(lane>>4)*4+reg  [m89]
    __syncthreads();                 // all waves done with u-buffer
    float* sred = reinterpret_cast<float*>(ubuf);
    float* dst  = sred + (wave & 1) * 1024;
    if (wave < 2) {
        #pragma unroll
        for (int ca = 0; ca < 2; ++ca)
            #pragma unroll
            for (int cb = 0; cb < 2; ++cb)
                #pragma unroll
                for (int r = 0; r < 4; ++r)
                    dst[(ca * 16 + g * 4 + r) * D_ + cb * 16 + cL] = acc[ca][cb][r];
    }
    __syncthreads();
    if (wave >= 2) {
        #pragma unroll
        for (int ca = 0; ca < 2; ++ca)
            #pragma unroll
            for (int cb = 0; cb < 2; ++cb)
                #pragma unroll
                for (int r = 0; r < 4; ++r)
                    dst[(ca * 16 + g * 4 + r) * D_ + cb * 16 + cL] += acc[ca][cb][r];
    }
    __syncthreads();
    {
        float* Sb = Sws + (size_t)bh * (D_ * D_);
        const float4 va = *reinterpret_cast<const float4*>(&sred[tid * 4]);
        const float4 vb = *reinterpret_cast<const float4*>(&sred[1024 + tid * 4]);
        atomicAdd(Sb + tid * 4 + 0, va.x + vb.x);
        atomicAdd(Sb + tid * 4 + 1, va.y + vb.y);
        atomicAdd(Sb + tid * 4 + 2, va.z + vb.z);
        atomicAdd(Sb + tid * 4 + 3, va.w + vb.w);
    }

    if (lane < 16) {                 // t: every reg holds t[col]; use reg 0
        atomicAdd(Tws + bh * D_ + cL,      tq[0][0]);
        atomicAdd(Tws + bh * D_ + 16 + cL, tq[1][0]);
    }
}

// ---------------------------------------------------------------------------
// Kernel 2: out[b,n,c] = x[b,n,c] + sum_d x[b,n,h*32+d] * kv[b,h][d][e]
// kv rebuilt from S,t with weights/biases folded in. (unchanged)
// ---------------------------------------------------------------------------
__global__ __launch_bounds__(256, 4)
void k2_out(const float* __restrict__ x,
            const float* __restrict__ Sws, const float* __restrict__ Tws,
            const float* __restrict__ kw, const float* __restrict__ kb,
            const float* __restrict__ vw, const float* __restrict__ vb,
            float* __restrict__ out)
{
    __shared__ float xbuf[4 * C_];

    const int tid   = threadIdx.x;
    const int b     = blockIdx.x >> 6;
    const int chunk = blockIdx.x & 63;
    const int h     = tid >> 5;
    const int e     = tid & 31;
    const int bh    = b * 8 + h;

    const float* S = Sws + (size_t)bh * (D_ * D_);
    const float* T = Tws + bh * D_;
    const float wve  = vw[h * D_ + e];
    const float bve  = vb[h * D_ + e];
    const float Te   = T[e];
    const float invN = 1.f / (float)N_;

    float kvc[32];
    #pragma unroll
    for (int d = 0; d < D_; ++d) {
        const float wkd = kw[h * D_ + d];
        const float bkd = kb[h * D_ + d];
        kvc[d] = invN * (wkd * (wve * S[d * D_ + e] + bve * T[d]) + bkd * wve * Te)
               + bkd * bve;
    }

    for (int it = 0; it < 16; ++it) {
        const int r0 = chunk * 64 + it * 4;
        const float* xrow = x + ((size_t)b * N_ + r0) * C_;
        const float4 xv = reinterpret_cast<const float4*>(xrow)[tid];
        __syncthreads();
        reinterpret_cast<float4*>(xbuf)[tid] = xv;
        __syncthreads();

        float res[4];
        #pragma unroll
        for (int r = 0; r < 4; ++r) {
            const float4* xr4 = reinterpret_cast<const float4*>(xbuf + r * C_ + h * D_);
            float dot = 0.f;
            #pragma unroll
            for (int c = 0; c < 8; ++c) {
                const float4 a = xr4[c];
                dot += a.x * kvc[c * 4 + 0] + a.y * kvc[c * 4 + 1]
                     + a.z * kvc[c * 4 + 2] + a.w * kvc[c * 4 + 3];
            }
            res[r] = dot + xbuf[r * C_ + tid];
        }
        float* orow = out + ((size_t)b * N_ + r0) * C_;
        #pragma unroll
        for (int r = 0; r < 4; ++r) orow[r * C_ + tid] = res[r];
    }
}

extern "C" void kernel_launch(void* const* d_in, const int* in_sizes, int n_in,
                              void* d_out, int out_size, void* d_ws, size_t ws_size,
                              hipStream_t stream)
{
    const float* x  = (const float*)d_in[0];
    const float* kw = (const float*)d_in[1];
    const float* kb = (const float*)d_in[2];
    const float* vw = (const float*)d_in[3];
    const float* vb = (const float*)d_in[4];
    float* outp = (float*)d_out;

    float* Sws = (float*)d_ws;
    float* Tws = Sws + (size_t)B_ * H_ * D_ * D_;
    const size_t zero_bytes =
        ((size_t)B_ * H_ * D_ * D_ + (size_t)B_ * H_ * D_) * sizeof(float);
    hipMemsetAsync(d_ws, 0, zero_bytes, stream);

    k1_skv<<<dim3(B_ * H_ * 16), dim3(256), 0, stream>>>(x, Sws, Tws);
    k2_out<<<dim3(B_ * 64), dim3(256), 0, stream>>>(x, Sws, Tws, kw, kb, vw, vb, outp);
}

// Round 6
// 101.274 us; speedup vs baseline: 1.2901x; 1.2901x over previous
//
#include <hip/hip_runtime.h>

#define H_ 8
#define D_ 32
#define B_ 32
#define N_ 4096
#define C_ 256
#define EPS_ 1e-5f

// per-block partial slot: 1024 floats S + 32 floats T, padded to 1088
#define SLOT_ 1088

typedef __attribute__((ext_vector_type(8))) short bf16x8;
typedef __attribute__((ext_vector_type(4))) float f32x4;

__device__ __forceinline__ short f2bf(float f) {
    unsigned u = __builtin_bit_cast(unsigned, f);
    unsigned r = (u + 0x7FFFu + ((u >> 16) & 1u)) >> 16;
    return (short)r;
}

// physical short-index of (row, col) in ubuf: 80 B row stride + 32 B shift per
// 8-row group -> fragment reads conflict-free (verified R2: 0 conflicts).
__device__ __forceinline__ int uidx(int r, int c) {
    return r * 40 + ((r >> 3) & 3) * 16 + c;
}

// ---------------------------------------------------------------------------
// Kernel 1: per (b,h) accumulate S = U^T U (32x32) and t = colsum(U) via MFMA.
// Grid: B*H*4 = 1024 blocks (1024 rows each, 4 iters x 256 rows), 256 threads.
// Thread tid owns row tid of each iter (lane-private LN). u-buffer stripes are
// WAVE-PRIVATE -> zero block barriers in the hot loop; software pipeline:
// next iter's 8 dwordx4 are issued before consuming the current iter.
// NO ATOMICS: each block writes its own partial slot (plain coalesced stores).
// ---------------------------------------------------------------------------
__global__ __launch_bounds__(256, 4)
void k1_skv(const float* __restrict__ x, float* __restrict__ Pws)
{
    __shared__ short ubuf[256 * 40 + 64];   // 20.6 KB; reused as float scratch

    const int tid  = threadIdx.x;
    const int bh   = blockIdx.x >> 2;
    const int q4   = blockIdx.x & 3;
    const int b    = bh >> 3;
    const int h    = bh & 7;
    const int lane = tid & 63;
    const int wave = tid >> 6;
    const int g    = lane >> 4;      // 0..3 : k-group
    const int cL   = lane & 15;      // 0..15: column within 16-block

    f32x4 acc[2][2] = {};            // S quadrants [ca][cb]
    f32x4 tq[2] = {};                // column sums via ones-MFMA

    bf16x8 ones;
    #pragma unroll
    for (int j = 0; j < 8; ++j) ones[j] = (short)0x3F80;   // bf16 1.0

    const float* xbase = x + ((size_t)b * N_ + q4 * 1024 + tid) * C_ + h * D_;

    float4 xA[8], xB[8];
    #pragma unroll
    for (int c = 0; c < 8; ++c)
        xA[c] = reinterpret_cast<const float4*>(xbase)[c];

    auto body = [&](const float4 (&xr)[8], float4 (&nx)[8], int it, bool pf) {
        // ---- prefetch next iter BEFORE consuming current (hides HBM latency)
        if (pf) {
            const float* p = xbase + (size_t)(it + 1) * 256 * C_;
            #pragma unroll
            for (int c = 0; c < 8; ++c)
                nx[c] = reinterpret_cast<const float4*>(p)[c];
        }

        // ---- LN, fully lane-private
        float sum = 0.f, sq = 0.f;
        #pragma unroll
        for (int c = 0; c < 8; ++c) {
            const float4 a = xr[c];
            sum += a.x + a.y + a.z + a.w;
            sq = fmaf(a.x, a.x, fmaf(a.y, a.y, fmaf(a.z, a.z, fmaf(a.w, a.w, sq))));
        }
        const float m   = sum * (1.f / 32.f);
        const float ss  = fmaxf(sq - sum * m, 0.f);
        const float inv = 1.f / (sqrtf(ss * (1.f / 31.f)) + EPS_);

        // ---- u -> bf16, write own row to LDS (wave-private stripe)
        {
            const int base = tid * 40 + ((tid >> 3) & 3) * 16;
            #pragma unroll
            for (int q = 0; q < 4; ++q) {
                const float4 a0 = xr[q * 2 + 0];
                const float4 a1 = xr[q * 2 + 1];
                bf16x8 wv;
                wv[0] = f2bf((a0.x - m) * inv); wv[1] = f2bf((a0.y - m) * inv);
                wv[2] = f2bf((a0.z - m) * inv); wv[3] = f2bf((a0.w - m) * inv);
                wv[4] = f2bf((a1.x - m) * inv); wv[5] = f2bf((a1.y - m) * inv);
                wv[6] = f2bf((a1.z - m) * inv); wv[7] = f2bf((a1.w - m) * inv);
                *reinterpret_cast<bf16x8*>(&ubuf[base + q * 8]) = wv;
            }
        }
        // intra-wave write->read ordering only; NO block barrier
        asm volatile("s_waitcnt lgkmcnt(0)" ::: "memory");

        // ---- fragment + MFMA: wave w owns K-rows [w*64, w*64+64), 2 ks-steps
        #pragma unroll
        for (int ks = 0; ks < 2; ++ks) {
            const int R0 = wave * 64 + ks * 32 + 8 * g;
            bf16x8 F0, F1;
            #pragma unroll
            for (int j = 0; j < 8; ++j) {
                const int base = uidx(R0 + j, cL);
                F0[j] = ubuf[base];
                F1[j] = ubuf[base + 16];
            }
            tq[0] = __builtin_amdgcn_mfma_f32_16x16x32_bf16(ones, F0, tq[0], 0, 0, 0);
            tq[1] = __builtin_amdgcn_mfma_f32_16x16x32_bf16(ones, F1, tq[1], 0, 0, 0);
            acc[0][0] = __builtin_amdgcn_mfma_f32_16x16x32_bf16(F0, F0, acc[0][0], 0, 0, 0);
            acc[0][1] = __builtin_amdgcn_mfma_f32_16x16x32_bf16(F0, F1, acc[0][1], 0, 0, 0);
            acc[1][0] = __builtin_amdgcn_mfma_f32_16x16x32_bf16(F1, F0, acc[1][0], 0, 0, 0);
            acc[1][1] = __builtin_amdgcn_mfma_f32_16x16x32_bf16(F1, F1, acc[1][1], 0, 0, 0);
        }
    };

    body(xA, xB, 0, true);
    body(xB, xA, 1, true);
    body(xA, xB, 2, true);
    body(xB, xA, 3, false);

    // ---- epilogue: 4 wave-private S copies in LDS, one barrier, plain stores
    // C/D layout col=lane&15, row=(lane>>4)*4+reg  [m89]
    __syncthreads();                 // all waves done with u-buffer
    float* sred = reinterpret_cast<float*>(ubuf);   // 4*1024 S + 128 T floats
    {
        float* dst = sred + wave * 1024;
        #pragma unroll
        for (int ca = 0; ca < 2; ++ca)
            #pragma unroll
            for (int cb = 0; cb < 2; ++cb)
                #pragma unroll
                for (int r = 0; r < 4; ++r)
                    dst[(ca * 16 + g * 4 + r) * D_ + cb * 16 + cL] = acc[ca][cb][r];
    }
    if (lane < 16) {                 // every reg holds t[col]; use reg 0
        sred[4096 + wave * 32 + cL]      = tq[0][0];
        sred[4096 + wave * 32 + 16 + cL] = tq[1][0];
    }
    __syncthreads();

    float* slot = Pws + (size_t)blockIdx.x * SLOT_;
    {
        const float4 c0 = *reinterpret_cast<const float4*>(&sred[tid * 4]);
        const float4 c1 = *reinterpret_cast<const float4*>(&sred[1024 + tid * 4]);
        const float4 c2 = *reinterpret_cast<const float4*>(&sred[2048 + tid * 4]);
        const float4 c3 = *reinterpret_cast<const float4*>(&sred[3072 + tid * 4]);
        float4 o;
        o.x = c0.x + c1.x + c2.x + c3.x;
        o.y = c0.y + c1.y + c2.y + c3.y;
        o.z = c0.z + c1.z + c2.z + c3.z;
        o.w = c0.w + c1.w + c2.w + c3.w;
        *reinterpret_cast<float4*>(slot + tid * 4) = o;   // coalesced 4 KB
    }
    if (tid < D_)
        slot[1024 + tid] = sred[4096 + tid] + sred[4096 + 32 + tid]
                         + sred[4096 + 64 + tid] + sred[4096 + 96 + tid];
}

// ---------------------------------------------------------------------------
// Kernel 2: out[b,n,c] = x[b,n,c] + sum_d x[b,n,h*32+d] * kv[b,h][d][e]
// kv rebuilt from the 4 partial slots (S,t) with weights/biases folded in.
// ---------------------------------------------------------------------------
__global__ __launch_bounds__(256, 4)
void k2_out(const float* __restrict__ x, const float* __restrict__ Pws,
            const float* __restrict__ kw, const float* __restrict__ kb,
            const float* __restrict__ vw, const float* __restrict__ vb,
            float* __restrict__ out)
{
    __shared__ float xbuf[4 * C_];

    const int tid   = threadIdx.x;
    const int b     = blockIdx.x >> 6;
    const int chunk = blockIdx.x & 63;
    const int h     = tid >> 5;
    const int e     = tid & 31;
    const int bh    = b * 8 + h;

    const float* P0 = Pws + (size_t)(bh * 4 + 0) * SLOT_;
    const float* P1 = Pws + (size_t)(bh * 4 + 1) * SLOT_;
    const float* P2 = Pws + (size_t)(bh * 4 + 2) * SLOT_;
    const float* P3 = Pws + (size_t)(bh * 4 + 3) * SLOT_;

    const float wve  = vw[h * D_ + e];
    const float bve  = vb[h * D_ + e];
    const float Te   = P0[1024 + e] + P1[1024 + e] + P2[1024 + e] + P3[1024 + e];
    const float invN = 1.f / (float)N_;

    float kvc[32];
    #pragma unroll
    for (int d = 0; d < D_; ++d) {
        const float Sde = P0[d * D_ + e] + P1[d * D_ + e]
                        + P2[d * D_ + e] + P3[d * D_ + e];
        const float Td  = P0[1024 + d] + P1[1024 + d] + P2[1024 + d] + P3[1024 + d];
        const float wkd = kw[h * D_ + d];
        const float bkd = kb[h * D_ + d];
        kvc[d] = invN * (wkd * (wve * Sde + bve * Td) + bkd * wve * Te)
               + bkd * bve;
    }

    for (int it = 0; it < 16; ++it) {
        const int r0 = chunk * 64 + it * 4;
        const float* xrow = x + ((size_t)b * N_ + r0) * C_;
        const float4 xv = reinterpret_cast<const float4*>(xrow)[tid];
        __syncthreads();
        reinterpret_cast<float4*>(xbuf)[tid] = xv;
        __syncthreads();

        float res[4];
        #pragma unroll
        for (int r = 0; r < 4; ++r) {
            const float4* xr4 = reinterpret_cast<const float4*>(xbuf + r * C_ + h * D_);
            float dot = 0.f;
            #pragma unroll
            for (int c = 0; c < 8; ++c) {
                const float4 a = xr4[c];
                dot += a.x * kvc[c * 4 + 0] + a.y * kvc[c * 4 + 1]
                     + a.z * kvc[c * 4 + 2] + a.w * kvc[c * 4 + 3];
            }
            res[r] = dot + xbuf[r * C_ + tid];
        }
        float* orow = out + ((size_t)b * N_ + r0) * C_;
        #pragma unroll
        for (int r = 0; r < 4; ++r) orow[r * C_ + tid] = res[r];
    }
}

extern "C" void kernel_launch(void* const* d_in, const int* in_sizes, int n_in,
                              void* d_out, int out_size, void* d_ws, size_t ws_size,
                              hipStream_t stream)
{
    const float* x  = (const float*)d_in[0];
    const float* kw = (const float*)d_in[1];
    const float* kb = (const float*)d_in[2];
    const float* vw = (const float*)d_in[3];
    const float* vb = (const float*)d_in[4];
    float* outp = (float*)d_out;

    float* Pws = (float*)d_ws;   // 1024 slots x 1088 floats = 4.46 MB

    k1_skv<<<dim3(B_ * H_ * 4), dim3(256), 0, stream>>>(x, Pws);
    k2_out<<<dim3(B_ * 64), dim3(256), 0, stream>>>(x, Pws, kw, kb, vw, vb, outp);
}

// Round 7
// 83.401 us; speedup vs baseline: 1.5666x; 1.2143x over previous
//
#include <hip/hip_runtime.h>

#define H_ 8
#define D_ 32
#define B_ 32
#define N_ 4096
#define C_ 256
#define EPS_ 1e-5f

// per-block partial slot: 1024 floats S + 32 floats T, padded to 1088
#define SLOT_ 1088

typedef __attribute__((ext_vector_type(8))) short bf16x8;
typedef __attribute__((ext_vector_type(4))) float f32x4;

__device__ __forceinline__ short f2bf(float f) {
    unsigned u = __builtin_bit_cast(unsigned, f);
    unsigned r = (u + 0x7FFFu + ((u >> 16) & 1u)) >> 16;
    return (short)r;
}

// physical short-index of (row, col) in ubuf: 80 B row stride + 32 B shift per
// 8-row group -> fragment reads conflict-free (verified R2: 0 conflicts).
__device__ __forceinline__ int uidx(int r, int c) {
    return r * 40 + ((r >> 3) & 3) * 16 + c;
}

// ---------------------------------------------------------------------------
// Kernel 1: per (b,h) accumulate S = U^T U (32x32) and t = colsum(U) via MFMA.
// Grid: B*H*4 = 1024 blocks (1024 rows each, 4 iters x 256 rows), 256 threads.
// Wave-private LDS stripes -> zero block barriers in hot loop; next iter's
// loads issued before consuming current. NO ATOMICS: per-block partial slots.
// (unchanged from R6 — measured ~16 µs)
// ---------------------------------------------------------------------------
__global__ __launch_bounds__(256, 4)
void k1_skv(const float* __restrict__ x, float* __restrict__ Pws)
{
    __shared__ short ubuf[256 * 40 + 64];   // 20.6 KB; reused as float scratch

    const int tid  = threadIdx.x;
    const int bh   = blockIdx.x >> 2;
    const int q4   = blockIdx.x & 3;
    const int b    = bh >> 3;
    const int h    = bh & 7;
    const int lane = tid & 63;
    const int wave = tid >> 6;
    const int g    = lane >> 4;      // 0..3 : k-group
    const int cL   = lane & 15;      // 0..15: column within 16-block

    f32x4 acc[2][2] = {};            // S quadrants [ca][cb]
    f32x4 tq[2] = {};                // column sums via ones-MFMA

    bf16x8 ones;
    #pragma unroll
    for (int j = 0; j < 8; ++j) ones[j] = (short)0x3F80;   // bf16 1.0

    const float* xbase = x + ((size_t)b * N_ + q4 * 1024 + tid) * C_ + h * D_;

    float4 xA[8], xB[8];
    #pragma unroll
    for (int c = 0; c < 8; ++c)
        xA[c] = reinterpret_cast<const float4*>(xbase)[c];

    auto body = [&](const float4 (&xr)[8], float4 (&nx)[8], int it, bool pf) {
        if (pf) {
            const float* p = xbase + (size_t)(it + 1) * 256 * C_;
            #pragma unroll
            for (int c = 0; c < 8; ++c)
                nx[c] = reinterpret_cast<const float4*>(p)[c];
        }

        float sum = 0.f, sq = 0.f;
        #pragma unroll
        for (int c = 0; c < 8; ++c) {
            const float4 a = xr[c];
            sum += a.x + a.y + a.z + a.w;
            sq = fmaf(a.x, a.x, fmaf(a.y, a.y, fmaf(a.z, a.z, fmaf(a.w, a.w, sq))));
        }
        const float m   = sum * (1.f / 32.f);
        const float ss  = fmaxf(sq - sum * m, 0.f);
        const float inv = 1.f / (sqrtf(ss * (1.f / 31.f)) + EPS_);

        {
            const int base = tid * 40 + ((tid >> 3) & 3) * 16;
            #pragma unroll
            for (int q = 0; q < 4; ++q) {
                const float4 a0 = xr[q * 2 + 0];
                const float4 a1 = xr[q * 2 + 1];
                bf16x8 wv;
                wv[0] = f2bf((a0.x - m) * inv); wv[1] = f2bf((a0.y - m) * inv);
                wv[2] = f2bf((a0.z - m) * inv); wv[3] = f2bf((a0.w - m) * inv);
                wv[4] = f2bf((a1.x - m) * inv); wv[5] = f2bf((a1.y - m) * inv);
                wv[6] = f2bf((a1.z - m) * inv); wv[7] = f2bf((a1.w - m) * inv);
                *reinterpret_cast<bf16x8*>(&ubuf[base + q * 8]) = wv;
            }
        }
        asm volatile("s_waitcnt lgkmcnt(0)" ::: "memory");

        #pragma unroll
        for (int ks = 0; ks < 2; ++ks) {
            const int R0 = wave * 64 + ks * 32 + 8 * g;
            bf16x8 F0, F1;
            #pragma unroll
            for (int j = 0; j < 8; ++j) {
                const int base = uidx(R0 + j, cL);
                F0[j] = ubuf[base];
                F1[j] = ubuf[base + 16];
            }
            tq[0] = __builtin_amdgcn_mfma_f32_16x16x32_bf16(ones, F0, tq[0], 0, 0, 0);
            tq[1] = __builtin_amdgcn_mfma_f32_16x16x32_bf16(ones, F1, tq[1], 0, 0, 0);
            acc[0][0] = __builtin_amdgcn_mfma_f32_16x16x32_bf16(F0, F0, acc[0][0], 0, 0, 0);
            acc[0][1] = __builtin_amdgcn_mfma_f32_16x16x32_bf16(F0, F1, acc[0][1], 0, 0, 0);
            acc[1][0] = __builtin_amdgcn_mfma_f32_16x16x32_bf16(F1, F0, acc[1][0], 0, 0, 0);
            acc[1][1] = __builtin_amdgcn_mfma_f32_16x16x32_bf16(F1, F1, acc[1][1], 0, 0, 0);
        }
    };

    body(xA, xB, 0, true);
    body(xB, xA, 1, true);
    body(xA, xB, 2, true);
    body(xB, xA, 3, false);

    // ---- epilogue: 4 wave-private S copies in LDS, one barrier, plain stores
    __syncthreads();
    float* sred = reinterpret_cast<float*>(ubuf);
    {
        float* dst = sred + wave * 1024;
        #pragma unroll
        for (int ca = 0; ca < 2; ++ca)
            #pragma unroll
            for (int cb = 0; cb < 2; ++cb)
                #pragma unroll
                for (int r = 0; r < 4; ++r)
                    dst[(ca * 16 + g * 4 + r) * D_ + cb * 16 + cL] = acc[ca][cb][r];
    }
    if (lane < 16) {
        sred[4096 + wave * 32 + cL]      = tq[0][0];
        sred[4096 + wave * 32 + 16 + cL] = tq[1][0];
    }
    __syncthreads();

    float* slot = Pws + (size_t)blockIdx.x * SLOT_;
    {
        const float4 c0 = *reinterpret_cast<const float4*>(&sred[tid * 4]);
        const float4 c1 = *reinterpret_cast<const float4*>(&sred[1024 + tid * 4]);
        const float4 c2 = *reinterpret_cast<const float4*>(&sred[2048 + tid * 4]);
        const float4 c3 = *reinterpret_cast<const float4*>(&sred[3072 + tid * 4]);
        float4 o;
        o.x = c0.x + c1.x + c2.x + c3.x;
        o.y = c0.y + c1.y + c2.y + c3.y;
        o.z = c0.z + c1.z + c2.z + c3.z;
        o.w = c0.w + c1.w + c2.w + c3.w;
        *reinterpret_cast<float4*>(slot + tid * 4) = o;
    }
    if (tid < D_)
        slot[1024 + tid] = sred[4096 + tid] + sred[4096 + 32 + tid]
                         + sred[4096 + 64 + tid] + sred[4096 + 96 + tid];
}

// ---------------------------------------------------------------------------
// Kernel 1b: reduce the 4 partial slots + fold weights/biases into the FINAL
// kv matrix per (b,h): kvF[bh][d][e]. Grid: 256 blocks (one per bh) x 256 thr.
// Thread handles 4 consecutive e's of one d. Total reads 4.4 MB (vs ~270 MB
// when every k2 thread rebuilt kv itself).
// ---------------------------------------------------------------------------
__global__ __launch_bounds__(256, 4)
void k_red(const float* __restrict__ Pws,
           const float* __restrict__ kw, const float* __restrict__ kb,
           const float* __restrict__ vw, const float* __restrict__ vb,
           float* __restrict__ kvF)
{
    const int bh  = blockIdx.x;       // 0..255
    const int h   = bh & 7;
    const int tid = threadIdx.x;
    const int d   = tid >> 3;         // 0..31
    const int e0  = (tid & 7) * 4;    // 0,4,..,28

    const float* P0 = Pws + (size_t)(bh * 4 + 0) * SLOT_;
    const float* P1 = Pws + (size_t)(bh * 4 + 1) * SLOT_;
    const float* P2 = Pws + (size_t)(bh * 4 + 2) * SLOT_;
    const float* P3 = Pws + (size_t)(bh * 4 + 3) * SLOT_;
    const float invN = 1.f / (float)N_;

    const float4 s0 = *reinterpret_cast<const float4*>(P0 + d * D_ + e0);
    const float4 s1 = *reinterpret_cast<const float4*>(P1 + d * D_ + e0);
    const float4 s2 = *reinterpret_cast<const float4*>(P2 + d * D_ + e0);
    const float4 s3 = *reinterpret_cast<const float4*>(P3 + d * D_ + e0);
    float Sde[4] = { s0.x + s1.x + s2.x + s3.x, s0.y + s1.y + s2.y + s3.y,
                     s0.z + s1.z + s2.z + s3.z, s0.w + s1.w + s2.w + s3.w };

    const float Td  = P0[1024 + d] + P1[1024 + d] + P2[1024 + d] + P3[1024 + d];
    const float wkd = kw[h * D_ + d];
    const float bkd = kb[h * D_ + d];

    float4 o;
    float* op = &o.x;
    #pragma unroll
    for (int j = 0; j < 4; ++j) {
        const int e = e0 + j;
        const float Te  = P0[1024 + e] + P1[1024 + e] + P2[1024 + e] + P3[1024 + e];
        const float wve = vw[h * D_ + e];
        const float bve = vb[h * D_ + e];
        op[j] = invN * (wkd * (wve * Sde[j] + bve * Td) + bkd * wve * Te)
              + bkd * bve;
    }
    *reinterpret_cast<float4*>(kvF + (size_t)bh * 1024 + tid * 4) = o;
}

// ---------------------------------------------------------------------------
// Kernel 2: out[b,n,c] = x[b,n,c] + sum_d x[b,n,h*32+d] * kvF[b,h][d][e].
// Grid: 2048 blocks x 256 threads. Each WAVE owns a 64-column stripe (heads
// 2w, 2w+1) x 64 rows: stages 4-row x 64-col chunks (one dwordx4/lane) into
// wave-private double-buffered LDS — ZERO block barriers, loads issued 2
// chunks ahead. ds_read_b128 fragment reads are 2-address broadcasts (free).
// ---------------------------------------------------------------------------
__global__ __launch_bounds__(256, 4)
void k2_out(const float* __restrict__ x, const float* __restrict__ kvF,
            float* __restrict__ out)
{
    __shared__ float lds[4][2][256];   // [wave][buf][4 rows x 64 cols] = 8 KB

    const int tid  = threadIdx.x;
    const int lane = tid & 63;
    const int w    = tid >> 6;         // wave = column stripe
    const int hloc = lane >> 5;        // 0..1
    const int e    = lane & 31;
    const int R0   = blockIdx.x * 64;  // 64 rows per block
    const int b    = R0 >> 12;         // N = 4096
    const int n0   = R0 & (N_ - 1);
    const int h    = 2 * w + hloc;

    // kv column e for head h, 32 coalesced loads (L2/L3-resident kvF)
    const float* kvp = kvF + ((size_t)(b * H_ + h)) * 1024 + e;
    float kvc[32];
    #pragma unroll
    for (int d = 0; d < D_; ++d) kvc[d] = kvp[d * D_];

    const int lrow = lane >> 4;        // 0..3 : row within 4-row chunk
    const int lcol = (lane & 15) * 4;  // float col within 64-col stripe
    const float* xg = x + ((size_t)b * N_ + n0 + lrow) * C_ + w * 64 + lcol;
    float* og = out + ((size_t)b * N_ + n0) * C_ + w * 64 + hloc * 32 + e;

    float* buf0 = &lds[w][0][0];
    float* buf1 = &lds[w][1][0];
    const int wslot = lrow * 64 + lcol;

    float4 pA = *reinterpret_cast<const float4*>(xg);
    float4 pB = *reinterpret_cast<const float4*>(xg + (size_t)4 * C_);

    #pragma unroll 4
    for (int t = 0; t < 16; ++t) {
        float* buf = (t & 1) ? buf1 : buf0;
        *reinterpret_cast<float4*>(buf + wslot) = pA;
        pA = pB;
        if (t + 2 < 16)
            pB = *reinterpret_cast<const float4*>(xg + (size_t)(t + 2) * 4 * C_);
        asm volatile("s_waitcnt lgkmcnt(0)" ::: "memory");

        #pragma unroll
        for (int r = 0; r < 4; ++r) {
            const float4* row4 =
                reinterpret_cast<const float4*>(buf + r * 64 + hloc * 32);
            float dot = 0.f;
            #pragma unroll
            for (int c = 0; c < 8; ++c) {
                const float4 a = row4[c];
                dot += a.x * kvc[c * 4 + 0] + a.y * kvc[c * 4 + 1]
                     + a.z * kvc[c * 4 + 2] + a.w * kvc[c * 4 + 3];
            }
            const float resx = buf[r * 64 + hloc * 32 + e];
            og[(size_t)(t * 4 + r) * C_] = dot + resx;
        }
    }
}

extern "C" void kernel_launch(void* const* d_in, const int* in_sizes, int n_in,
                              void* d_out, int out_size, void* d_ws, size_t ws_size,
                              hipStream_t stream)
{
    const float* x  = (const float*)d_in[0];
    const float* kw = (const float*)d_in[1];
    const float* kb = (const float*)d_in[2];
    const float* vw = (const float*)d_in[3];
    const float* vb = (const float*)d_in[4];
    float* outp = (float*)d_out;

    float* Pws = (float*)d_ws;                       // 1024 x 1088 floats (4.46 MB)
    float* kvF = Pws + (size_t)1024 * SLOT_;         // 256 x 1024 floats (1 MB)

    k1_skv<<<dim3(B_ * H_ * 4), dim3(256), 0, stream>>>(x, Pws);
    k_red<<<dim3(B_ * H_), dim3(256), 0, stream>>>(Pws, kw, kb, vw, vb, kvF);
    k2_out<<<dim3(B_ * N_ / 64), dim3(256), 0, stream>>>(x, kvF, outp);
}

// Round 8
// 81.237 us; speedup vs baseline: 1.6083x; 1.0266x over previous
//
#include <hip/hip_runtime.h>

#define H_ 8
#define D_ 32
#define B_ 32
#define N_ 4096
#define C_ 256
#define EPS_ 1e-5f

// per-block partial slot: 1024 floats S + 32 floats T, padded to 1088
#define SLOT_ 1088

typedef __attribute__((ext_vector_type(8))) short bf16x8;
typedef __attribute__((ext_vector_type(4))) float f32x4;

__device__ __forceinline__ short f2bf(float f) {
    unsigned u = __builtin_bit_cast(unsigned, f);
    unsigned r = (u + 0x7FFFu + ((u >> 16) & 1u)) >> 16;
    return (short)r;
}
__device__ __forceinline__ float bf2f(short s) {
    return __builtin_bit_cast(float, ((unsigned)(unsigned short)s) << 16);
}

// physical short-index of (row, col) in ubuf: 80 B row stride + 32 B shift per
// 8-row group -> fragment reads conflict-free (verified R2: 0 conflicts).
__device__ __forceinline__ int uidx(int r, int c) {
    return r * 40 + ((r >> 3) & 3) * 16 + c;
}

// ---------------------------------------------------------------------------
// Kernel 1: per (b,h) accumulate S = U^T U (32x32) and t = colsum(U) via MFMA.
// (unchanged from R6/R7 — measured ~16 µs)
// ---------------------------------------------------------------------------
__global__ __launch_bounds__(256, 4)
void k1_skv(const float* __restrict__ x, float* __restrict__ Pws)
{
    __shared__ short ubuf[256 * 40 + 64];

    const int tid  = threadIdx.x;
    const int bh   = blockIdx.x >> 2;
    const int q4   = blockIdx.x & 3;
    const int b    = bh >> 3;
    const int h    = bh & 7;
    const int lane = tid & 63;
    const int wave = tid >> 6;
    const int g    = lane >> 4;
    const int cL   = lane & 15;

    f32x4 acc[2][2] = {};
    f32x4 tq[2] = {};

    bf16x8 ones;
    #pragma unroll
    for (int j = 0; j < 8; ++j) ones[j] = (short)0x3F80;

    const float* xbase = x + ((size_t)b * N_ + q4 * 1024 + tid) * C_ + h * D_;

    float4 xA[8], xB[8];
    #pragma unroll
    for (int c = 0; c < 8; ++c)
        xA[c] = reinterpret_cast<const float4*>(xbase)[c];

    auto body = [&](const float4 (&xr)[8], float4 (&nx)[8], int it, bool pf) {
        if (pf) {
            const float* p = xbase + (size_t)(it + 1) * 256 * C_;
            #pragma unroll
            for (int c = 0; c < 8; ++c)
                nx[c] = reinterpret_cast<const float4*>(p)[c];
        }

        float sum = 0.f, sq = 0.f;
        #pragma unroll
        for (int c = 0; c < 8; ++c) {
            const float4 a = xr[c];
            sum += a.x + a.y + a.z + a.w;
            sq = fmaf(a.x, a.x, fmaf(a.y, a.y, fmaf(a.z, a.z, fmaf(a.w, a.w, sq))));
        }
        const float m   = sum * (1.f / 32.f);
        const float ss  = fmaxf(sq - sum * m, 0.f);
        const float inv = 1.f / (sqrtf(ss * (1.f / 31.f)) + EPS_);

        {
            const int base = tid * 40 + ((tid >> 3) & 3) * 16;
            #pragma unroll
            for (int q = 0; q < 4; ++q) {
                const float4 a0 = xr[q * 2 + 0];
                const float4 a1 = xr[q * 2 + 1];
                bf16x8 wv;
                wv[0] = f2bf((a0.x - m) * inv); wv[1] = f2bf((a0.y - m) * inv);
                wv[2] = f2bf((a0.z - m) * inv); wv[3] = f2bf((a0.w - m) * inv);
                wv[4] = f2bf((a1.x - m) * inv); wv[5] = f2bf((a1.y - m) * inv);
                wv[6] = f2bf((a1.z - m) * inv); wv[7] = f2bf((a1.w - m) * inv);
                *reinterpret_cast<bf16x8*>(&ubuf[base + q * 8]) = wv;
            }
        }
        asm volatile("s_waitcnt lgkmcnt(0)" ::: "memory");

        #pragma unroll
        for (int ks = 0; ks < 2; ++ks) {
            const int R0 = wave * 64 + ks * 32 + 8 * g;
            bf16x8 F0, F1;
            #pragma unroll
            for (int j = 0; j < 8; ++j) {
                const int base = uidx(R0 + j, cL);
                F0[j] = ubuf[base];
                F1[j] = ubuf[base + 16];
            }
            tq[0] = __builtin_amdgcn_mfma_f32_16x16x32_bf16(ones, F0, tq[0], 0, 0, 0);
            tq[1] = __builtin_amdgcn_mfma_f32_16x16x32_bf16(ones, F1, tq[1], 0, 0, 0);
            acc[0][0] = __builtin_amdgcn_mfma_f32_16x16x32_bf16(F0, F0, acc[0][0], 0, 0, 0);
            acc[0][1] = __builtin_amdgcn_mfma_f32_16x16x32_bf16(F0, F1, acc[0][1], 0, 0, 0);
            acc[1][0] = __builtin_amdgcn_mfma_f32_16x16x32_bf16(F1, F0, acc[1][0], 0, 0, 0);
            acc[1][1] = __builtin_amdgcn_mfma_f32_16x16x32_bf16(F1, F1, acc[1][1], 0, 0, 0);
        }
    };

    body(xA, xB, 0, true);
    body(xB, xA, 1, true);
    body(xA, xB, 2, true);
    body(xB, xA, 3, false);

    __syncthreads();
    float* sred = reinterpret_cast<float*>(ubuf);
    {
        float* dst = sred + wave * 1024;
        #pragma unroll
        for (int ca = 0; ca < 2; ++ca)
            #pragma unroll
            for (int cb = 0; cb < 2; ++cb)
                #pragma unroll
                for (int r = 0; r < 4; ++r)
                    dst[(ca * 16 + g * 4 + r) * D_ + cb * 16 + cL] = acc[ca][cb][r];
    }
    if (lane < 16) {
        sred[4096 + wave * 32 + cL]      = tq[0][0];
        sred[4096 + wave * 32 + 16 + cL] = tq[1][0];
    }
    __syncthreads();

    float* slot = Pws + (size_t)blockIdx.x * SLOT_;
    {
        const float4 c0 = *reinterpret_cast<const float4*>(&sred[tid * 4]);
        const float4 c1 = *reinterpret_cast<const float4*>(&sred[1024 + tid * 4]);
        const float4 c2 = *reinterpret_cast<const float4*>(&sred[2048 + tid * 4]);
        const float4 c3 = *reinterpret_cast<const float4*>(&sred[3072 + tid * 4]);
        float4 o;
        o.x = c0.x + c1.x + c2.x + c3.x;
        o.y = c0.y + c1.y + c2.y + c3.y;
        o.z = c0.z + c1.z + c2.z + c3.z;
        o.w = c0.w + c1.w + c2.w + c3.w;
        *reinterpret_cast<float4*>(slot + tid * 4) = o;
    }
    if (tid < D_)
        slot[1024 + tid] = sred[4096 + tid] + sred[4096 + 32 + tid]
                         + sred[4096 + 64 + tid] + sred[4096 + 96 + tid];
}

// ---------------------------------------------------------------------------
// Kernel 1b: reduce partial slots + fold weights/biases -> kv, emitted as
// PRE-PACKED bf16 MFMA B-fragments, hi+lo split (kv error ~2^-17).
// B-frag layout: lane l, reg j <-> kv[d = 8*(l>>4)+j][e = 16*hf + (l&15)];
// stored at kv{Hi,Lo}[bh*1024 + hf*512 + l*8 + j].
// ---------------------------------------------------------------------------
__global__ __launch_bounds__(256, 4)
void k_red(const float* __restrict__ Pws,
           const float* __restrict__ kw, const float* __restrict__ kb,
           const float* __restrict__ vw, const float* __restrict__ vb,
           short* __restrict__ kvHi, short* __restrict__ kvLo)
{
    const int bh  = blockIdx.x;       // 0..255
    const int h   = bh & 7;
    const int tid = threadIdx.x;
    const int d   = tid >> 3;         // 0..31
    const int e0  = (tid & 7) * 4;    // 0,4,..,28

    const float* P0 = Pws + (size_t)(bh * 4 + 0) * SLOT_;
    const float* P1 = Pws + (size_t)(bh * 4 + 1) * SLOT_;
    const float* P2 = Pws + (size_t)(bh * 4 + 2) * SLOT_;
    const float* P3 = Pws + (size_t)(bh * 4 + 3) * SLOT_;
    const float invN = 1.f / (float)N_;

    const float4 s0 = *reinterpret_cast<const float4*>(P0 + d * D_ + e0);
    const float4 s1 = *reinterpret_cast<const float4*>(P1 + d * D_ + e0);
    const float4 s2 = *reinterpret_cast<const float4*>(P2 + d * D_ + e0);
    const float4 s3 = *reinterpret_cast<const float4*>(P3 + d * D_ + e0);
    float Sde[4] = { s0.x + s1.x + s2.x + s3.x, s0.y + s1.y + s2.y + s3.y,
                     s0.z + s1.z + s2.z + s3.z, s0.w + s1.w + s2.w + s3.w };

    const float Td  = P0[1024 + d] + P1[1024 + d] + P2[1024 + d] + P3[1024 + d];
    const float wkd = kw[h * D_ + d];
    const float bkd = kb[h * D_ + d];

    #pragma unroll
    for (int j = 0; j < 4; ++j) {
        const int e = e0 + j;
        const float Te  = P0[1024 + e] + P1[1024 + e] + P2[1024 + e] + P3[1024 + e];
        const float wve = vw[h * D_ + e];
        const float bve = vb[h * D_ + e];
        const float v = invN * (wkd * (wve * Sde[j] + bve * Td) + bkd * wve * Te)
                      + bkd * bve;
        const short hi = f2bf(v);
        const short lo = f2bf(v - bf2f(hi));
        const int hf  = e >> 4;
        const int l   = ((d >> 3) << 4) | (e & 15);
        const int idx = bh * 1024 + hf * 512 + l * 8 + (d & 7);
        kvHi[idx] = hi;
        kvLo[idx] = lo;
    }
}

// ---------------------------------------------------------------------------
// Kernel 2: out[n,c] = x[n,c] + (Q_head · kv_head)[n,c] via MFMA.
// Grid: 2048 blocks x 256 thr; wave owns 16 rows. Stage 16 rows fp32 into
// WAVE-PRIVATE LDS stripe (zero block barriers), 8 A-frags (ds_read_b128 x2
// + cvt), 2 MFMAs per (head, half) with hi+lo kv B-frags, residual added
// from fp32 LDS, direct frag stores.  ~90 LDS ops/thread vs 512 before.
// ---------------------------------------------------------------------------
__global__ __launch_bounds__(256, 2)
void k2_out(const float* __restrict__ x,
            const short* __restrict__ kvHi, const short* __restrict__ kvLo,
            float* __restrict__ out)
{
    __shared__ float xt[64][256];      // 64 KB, wave-private 16-row stripes

    const int tid  = threadIdx.x;
    const int lane = tid & 63;
    const int w    = tid >> 6;
    const int g    = lane >> 4;        // quarter-wave
    const int cL   = lane & 15;
    const int r0   = blockIdx.x * 64;  // flat row over B*N
    const int b    = blockIdx.x >> 6;  // 64 blocks per batch (4096/64)
    const int wr   = w * 16;

    // ---- B-fragments for 8 heads x 2 col-halves, hi+lo (L2-resident)
    bf16x8 Bhi[16], Blo[16];
    #pragma unroll
    for (int h = 0; h < 8; ++h)
        #pragma unroll
        for (int hf = 0; hf < 2; ++hf) {
            const size_t off = (size_t)(b * H_ + h) * 1024 + hf * 512 + lane * 8;
            Bhi[h * 2 + hf] = *reinterpret_cast<const bf16x8*>(kvHi + off);
            Blo[h * 2 + hf] = *reinterpret_cast<const bf16x8*>(kvLo + off);
        }

    // ---- stage my wave's 16 rows (fp32, coalesced, wave-private)
    const float* gx = x + (size_t)(r0 + wr) * C_ + lane * 4;
    {
        float4 v[8];
        #pragma unroll
        for (int i = 0; i < 8; ++i)
            v[i] = *reinterpret_cast<const float4*>(gx + (size_t)i * C_);
        #pragma unroll
        for (int i = 0; i < 8; ++i)
            *reinterpret_cast<float4*>(&xt[wr + i][lane * 4]) = v[i];
        #pragma unroll
        for (int i = 0; i < 8; ++i)
            v[i] = *reinterpret_cast<const float4*>(gx + (size_t)(i + 8) * C_);
        #pragma unroll
        for (int i = 0; i < 8; ++i)
            *reinterpret_cast<float4*>(&xt[wr + 8 + i][lane * 4]) = v[i];
    }
    // wave-private write->read ordering only; NO block barrier
    asm volatile("s_waitcnt lgkmcnt(0)" ::: "memory");
    __builtin_amdgcn_sched_barrier(0);

    const f32x4 zero = {0.f, 0.f, 0.f, 0.f};

    #pragma unroll
    for (int h = 0; h < 8; ++h) {
        // A-frag: lane holds q[row wr+cL][d = 8g..8g+8) as bf16
        const float4 a0 = *reinterpret_cast<const float4*>(&xt[wr + cL][h * 32 + 8 * g]);
        const float4 a1 = *reinterpret_cast<const float4*>(&xt[wr + cL][h * 32 + 8 * g + 4]);
        bf16x8 A;
        A[0] = f2bf(a0.x); A[1] = f2bf(a0.y); A[2] = f2bf(a0.z); A[3] = f2bf(a0.w);
        A[4] = f2bf(a1.x); A[5] = f2bf(a1.y); A[6] = f2bf(a1.z); A[7] = f2bf(a1.w);

        #pragma unroll
        for (int hf = 0; hf < 2; ++hf) {
            f32x4 Dv = __builtin_amdgcn_mfma_f32_16x16x32_bf16(A, Blo[h * 2 + hf], zero, 0, 0, 0);
            Dv = __builtin_amdgcn_mfma_f32_16x16x32_bf16(A, Bhi[h * 2 + hf], Dv, 0, 0, 0);
            const int col = h * 32 + hf * 16 + cL;
            #pragma unroll
            for (int r = 0; r < 4; ++r) {
                const int rr = wr + 4 * g + r;          // D row = 4*(l>>4)+reg
                out[(size_t)(r0 + rr) * C_ + col] = Dv[r] + xt[rr][col];
            }
        }
    }
}

extern "C" void kernel_launch(void* const* d_in, const int* in_sizes, int n_in,
                              void* d_out, int out_size, void* d_ws, size_t ws_size,
                              hipStream_t stream)
{
    const float* x  = (const float*)d_in[0];
    const float* kw = (const float*)d_in[1];
    const float* kb = (const float*)d_in[2];
    const float* vw = (const float*)d_in[3];
    const float* vb = (const float*)d_in[4];
    float* outp = (float*)d_out;

    float* Pws  = (float*)d_ws;                          // 1024 x 1088 floats (4.46 MB)
    short* kvHi = (short*)(Pws + (size_t)1024 * SLOT_);  // 256 x 1024 shorts (512 KB)
    short* kvLo = kvHi + (size_t)256 * 1024;             // 256 x 1024 shorts (512 KB)

    k1_skv<<<dim3(B_ * H_ * 4), dim3(256), 0, stream>>>(x, Pws);
    k_red<<<dim3(B_ * H_), dim3(256), 0, stream>>>(Pws, kw, kb, vw, vb, kvHi, kvLo);
    k2_out<<<dim3(B_ * N_ / 64), dim3(256), 0, stream>>>(x, kvHi, kvLo, outp);
}